// Round 13
// baseline (362.594 us; speedup 1.0000x reference)
//
#include <hip/hip_runtime.h>
#include <hip/hip_bf16.h>

#define DEV __device__ __forceinline__

typedef __attribute__((ext_vector_type(8))) short bf16x8;
typedef __attribute__((ext_vector_type(4))) float f32x4;
typedef __attribute__((ext_vector_type(4))) short short4v;
typedef __attribute__((ext_vector_type(2))) unsigned uint2v;

DEV short f2bf(float f) {
    union { float f; unsigned u; } x; x.f = f;
    unsigned u = x.u;
    unsigned r = (u + 0x7fffu + ((u >> 16) & 1u)) >> 16;
    return (short)r;
}

DEV float bf2f(short s) {
    union { unsigned u; float f; } x;
    x.u = ((unsigned)(unsigned short)s) << 16;
    return x.f;
}

// pack 2 f32 -> 2 bf16 in one u32 (lo = a, hi = b)
DEV unsigned cvtpk(float a, float b) {
    unsigned r;
    asm("v_cvt_pk_bf16_f32 %0, %1, %2" : "=v"(r) : "v"(a), "v"(b));
    return r;
}

// async global->LDS, 16B per lane; LDS dest = wave-uniform base + lane*16
#define GLD16(g, l)                                                         \
    __builtin_amdgcn_global_load_lds(                                       \
        (const __attribute__((address_space(1))) void*)(g),                 \
        (__attribute__((address_space(3))) void*)(l), 16, 0, 0)

#define WAITV(n) asm volatile("s_waitcnt vmcnt(" #n ")" ::: "memory")
#define SBAR()   asm volatile("s_barrier" ::: "memory")
#define LGKMDRAIN() asm volatile("s_waitcnt lgkmcnt(0)" ::: "memory")

// ---------------- prep kernels ----------------

__global__ __launch_bounds__(256) void k_cast(const float* __restrict__ in,
                                              short* __restrict__ out, int n4) {
    int i = blockIdx.x * 256 + threadIdx.x;
    if (i >= n4) return;
    float4 v = ((const float4*)in)[i];
    short4v o;
    o[0] = f2bf(v.x); o[1] = f2bf(v.y); o[2] = f2bf(v.z); o[3] = f2bf(v.w);
    ((short4v*)out)[i] = o;
}

// tiled transpose+cast: out[(c)*R + r] = bf16(in[r*C + c]); R,C multiples of 64
__global__ __launch_bounds__(256) void k_tr(const float* __restrict__ in,
                                            short* __restrict__ out,
                                            int R, int C,
                                            long in_hs, long out_hs) {
    in  += (size_t)blockIdx.z * in_hs;
    out += (size_t)blockIdx.z * out_hs;
    __shared__ short tile[64][68];
    const int t = threadIdx.x;
    const int r0 = blockIdx.y * 64, c0 = blockIdx.x * 64;
    const int lr = t >> 4, lc4 = (t & 15) * 4;
#pragma unroll
    for (int it = 0; it < 4; ++it) {
        int r = lr + it * 16;
        float4 v = *(const float4*)(in + (size_t)(r0 + r) * C + c0 + lc4);
        tile[lc4 + 0][r] = f2bf(v.x);
        tile[lc4 + 1][r] = f2bf(v.y);
        tile[lc4 + 2][r] = f2bf(v.z);
        tile[lc4 + 3][r] = f2bf(v.w);
    }
    __syncthreads();
#pragma unroll
    for (int it = 0; it < 4; ++it) {
        int c = lr + it * 16;
        short4v o;
        o[0] = tile[c][lc4 + 0];
        o[1] = tile[c][lc4 + 1];
        o[2] = tile[c][lc4 + 2];
        o[3] = tile[c][lc4 + 3];
        *(short4v*)(out + (size_t)(c0 + c) * R + r0 + lc4) = o;
    }
}

// merged QKV per-head transpose: z in [0,48): p=z/16 selects Wq/Wk/Wv,
// h=z%16 the head. R=1024, C=64. out laid [p][h][64 k][1024 d].
__global__ __launch_bounds__(256) void k_tr3(const float* __restrict__ Wq,
                                             const float* __restrict__ Wk,
                                             const float* __restrict__ Wv,
                                             short* __restrict__ out) {
    const int z = blockIdx.z;
    const float* in = ((z < 16) ? Wq : (z < 32) ? Wk : Wv) +
                      (size_t)(z & 15) * 65536;
    short* o = out + (size_t)z * 65536;
    __shared__ short tile[64][68];
    const int t = threadIdx.x;
    const int r0 = blockIdx.y * 64;
    const int lr = t >> 4, lc4 = (t & 15) * 4;
#pragma unroll
    for (int it = 0; it < 4; ++it) {
        int r = lr + it * 16;
        float4 v = *(const float4*)(in + (size_t)(r0 + r) * 64 + lc4);
        tile[lc4 + 0][r] = f2bf(v.x);
        tile[lc4 + 1][r] = f2bf(v.y);
        tile[lc4 + 2][r] = f2bf(v.z);
        tile[lc4 + 3][r] = f2bf(v.w);
    }
    __syncthreads();
#pragma unroll
    for (int it = 0; it < 4; ++it) {
        int c = lr + it * 16;
        short4v ov;
        ov[0] = tile[c][lc4 + 0];
        ov[1] = tile[c][lc4 + 1];
        ov[2] = tile[c][lc4 + 2];
        ov[3] = tile[c][lc4 + 3];
        *(short4v*)(o + (size_t)c * 1024 + r0 + lc4) = ov;
    }
}

// ======== 256x256 GEMM, 2-barrier K-loop (R12, measured = R9) ===============
// C = A[M,K] * BT[N,K]^T. 512 thr = 8 waves (2M x 4N), wave tile 128x64, BK=64.
// blockIdx.z = split-K slice over K range [z*NT*64, (z+1)*NT*64).
// MODE 0: QKV scatter epilogue (Q pre-scaled by 1/8*log2e);
// MODE 2: bf16 relu(acc+bias);
// MODE 3: bf16 split-K partial -- slices 0..2 -> o0 + z*M*N, slice 3 -> o1
template <int MODE>
__global__ __launch_bounds__(512, 2) void k_gemm8(
    const short* __restrict__ A, const short* __restrict__ BT,
    int K, int NT,
    const float* __restrict__ f0, const float* __restrict__ f1,
    const float* __restrict__ f2,
    void* __restrict__ o0, void* __restrict__ o1, void* __restrict__ o2) {
    __shared__ short lds[2][2][2][128 * 64];   // [buf][op A=0,B=1][half][r*64+c]
    const int t = threadIdx.x;
    const int w = t >> 6, l = t & 63;
    const int l16 = l & 15, lg = l >> 4;
    const int wm = w >> 2, wn = w & 3;
    const int bn = blockIdx.x, bm = blockIdx.y;
    const int koff = blockIdx.z * NT * 64;
    const short* Ab = A + (size_t)bm * 256 * K + koff;
    const short* Bb = BT + (size_t)bn * 256 * K + koff;
    const int srow = l >> 3;                    // staging row within 8-row group
    const int scol = ((l & 7) ^ srow) * 8;      // pre-swizzled source col (shorts)
    const int offk0 = ((0 + lg) ^ (l16 & 7)) * 8;  // swizzled ds_read chunk, kk=0
    const int offk1 = ((4 + lg) ^ (l16 & 7)) * 8;  // kk=1

    f32x4 acc[8][4] = {};

    auto stg = [&](int buf, int op, int h, int kt) {
#pragma unroll
        for (int i = 0; i < 2; ++i) {
            int row = h * 128 + w * 16 + i * 8 + srow;
            GLD16((op ? Bb : Ab) + (size_t)row * K + (size_t)kt * 64 + scol,
                  &lds[buf][op][h][(w * 16 + i * 8) * 64]);
        }
    };

    // prologue: A(0),B(0)->buf0 (8 loads); B(t1)->buf1 (4 loads)
    stg(0, 0, 0, 0); stg(0, 0, 1, 0);
    stg(0, 1, 0, 0); stg(0, 1, 1, 0);
    const int t1p = (NT > 1) ? 1 : 0;
    stg(1, 1, 0, t1p); stg(1, 1, 1, t1p);
    WAITV(4);   // tile0 landed; B(t1) 4 loads in flight
    SBAR();

    for (int kt = 0; kt < NT; ++kt) {
        const int cur = kt & 1, nxt = cur ^ 1;
        const int t1 = (kt + 1 < NT) ? kt + 1 : NT - 1;
        const int t2 = (kt + 2 < NT) ? kt + 2 : NT - 1;

        // early stage: A(t1)->nxt (no reader conflict; hides under compute)
        stg(nxt, 0, 0, t1); stg(nxt, 0, 1, t1);

        bf16x8 a0[4][2], a1[4][2], b0[2][2], b1[2][2];
#pragma unroll
        for (int m = 0; m < 4; ++m) {
            a0[m][0] = *(const bf16x8*)&lds[cur][0][wm][(m * 16 + l16) * 64 + offk0];
            a0[m][1] = *(const bf16x8*)&lds[cur][0][wm][(m * 16 + l16) * 64 + offk1];
        }
#pragma unroll
        for (int n = 0; n < 2; ++n) {
            int r = (wn & 1) * 64 + n * 16 + l16;
            b0[n][0] = *(const bf16x8*)&lds[cur][1][wn >> 1][r * 64 + offk0];
            b0[n][1] = *(const bf16x8*)&lds[cur][1][wn >> 1][r * 64 + offk1];
            int r2 = (wn & 1) * 64 + (n + 2) * 16 + l16;
            b1[n][0] = *(const bf16x8*)&lds[cur][1][wn >> 1][r2 * 64 + offk0];
            b1[n][1] = *(const bf16x8*)&lds[cur][1][wn >> 1][r2 * 64 + offk1];
        }
        __builtin_amdgcn_s_setprio(1);
#pragma unroll
        for (int m = 0; m < 4; ++m)
#pragma unroll
            for (int n = 0; n < 2; ++n) {
                acc[m][n] = __builtin_amdgcn_mfma_f32_16x16x32_bf16(a0[m][0], b0[n][0], acc[m][n], 0, 0, 0);
                acc[m][n] = __builtin_amdgcn_mfma_f32_16x16x32_bf16(a0[m][1], b0[n][1], acc[m][n], 0, 0, 0);
                acc[m][n + 2] = __builtin_amdgcn_mfma_f32_16x16x32_bf16(a0[m][0], b1[n][0], acc[m][n + 2], 0, 0, 0);
                acc[m][n + 2] = __builtin_amdgcn_mfma_f32_16x16x32_bf16(a0[m][1], b1[n][1], acc[m][n + 2], 0, 0, 0);
            }
        __builtin_amdgcn_s_setprio(0);
#pragma unroll
        for (int m = 0; m < 4; ++m) {
            a1[m][0] = *(const bf16x8*)&lds[cur][0][wm][((m + 4) * 16 + l16) * 64 + offk0];
            a1[m][1] = *(const bf16x8*)&lds[cur][0][wm][((m + 4) * 16 + l16) * 64 + offk1];
        }
        __builtin_amdgcn_s_setprio(1);
#pragma unroll
        for (int m = 0; m < 4; ++m)
#pragma unroll
            for (int n = 0; n < 2; ++n) {
                acc[m + 4][n + 2] = __builtin_amdgcn_mfma_f32_16x16x32_bf16(a1[m][0], b1[n][0], acc[m + 4][n + 2], 0, 0, 0);
                acc[m + 4][n + 2] = __builtin_amdgcn_mfma_f32_16x16x32_bf16(a1[m][1], b1[n][1], acc[m + 4][n + 2], 0, 0, 0);
                acc[m + 4][n] = __builtin_amdgcn_mfma_f32_16x16x32_bf16(a1[m][0], b0[n][0], acc[m + 4][n], 0, 0, 0);
                acc[m + 4][n] = __builtin_amdgcn_mfma_f32_16x16x32_bf16(a1[m][1], b0[n][1], acc[m + 4][n], 0, 0, 0);
            }
        __builtin_amdgcn_s_setprio(0);

        LGKMDRAIN();   // all cur reads retired in this wave
        SBAR();        // ... in every wave -> safe to overwrite cur-B
        stg(cur, 1, 0, t2); stg(cur, 1, 1, t2);   // B(t2)->cur (4 loads)
        WAITV(4);      // A(t1),B(t1) retired; only B(t2)'s 4 in flight
        SBAR();        // all waves -> t1 fully in LDS
    }
    WAITV(0);          // retire clamped trailing stages before exit

    const int N = gridDim.x * 256;
#pragma unroll
    for (int m = 0; m < 8; ++m) {
        int rowbase = bm * 256 + wm * 128 + m * 16 + lg * 4;
#pragma unroll
        for (int n = 0; n < 4; ++n) {
            int col = bn * 256 + wn * 64 + n * 16 + l16;
            if constexpr (MODE == 0) {
                int p = col >> 10, c1 = col & 1023;
                int hh = c1 >> 6, dk = c1 & 63;
                const float* bias = (p == 0) ? f0 : (p == 1) ? f1 : f2;
                float bvl = bias[c1];
                // fold softmax scale*log2e into Q
                float qs = (p == 0) ? 0.18033688011112042f : 1.0f;
                int b = rowbase >> 10, s = rowbase & 1023;
                if (p == 2) {
                    short4v vv;
#pragma unroll
                    for (int rr = 0; rr < 4; ++rr) vv[rr] = f2bf(acc[m][n][rr] + bvl);
                    *(short4v*)((short*)o2 + (((size_t)(b * 16 + hh) * 64 + dk) << 10) + s) = vv;
                } else {
                    short* dst = (p == 0) ? (short*)o0 : (short*)o1;
#pragma unroll
                    for (int rr = 0; rr < 4; ++rr)
                        dst[(((size_t)(b * 16 + hh) << 10) + s + rr) * 64 + dk] =
                            f2bf((acc[m][n][rr] + bvl) * qs);
                }
            } else if constexpr (MODE == 2) {
                float bvl = f0[col];
#pragma unroll
                for (int rr = 0; rr < 4; ++rr) {
                    size_t idx = (size_t)(rowbase + rr) * N + col;
                    float y = acc[m][n][rr] + bvl;
                    ((short*)o0)[idx] = f2bf(y > 0.f ? y : 0.f);
                }
            } else {  // MODE 3: bf16 split-K partial; z<3 -> o0+z*M*N, z=3 -> o1
                const int Mtot = gridDim.y * 256;
                short* dst = (blockIdx.z < 3)
                    ? (short*)o0 + (size_t)blockIdx.z * Mtot * N
                    : (short*)o1;
                size_t base = (size_t)rowbase * N + col;
#pragma unroll
                for (int rr = 0; rr < 4; ++rr)
                    dst[base + (size_t)rr * N] = f2bf(acc[m][n][rr]);
            }
        }
    }
}

// ------- flash attention R13: 8 waves x 32 q-rows (QBLK=256) ---------------
// grid (64, 4): blockIdx.x = b*16+h, blockIdx.y = q-block of 256 rows.
// Each wave owns 32 q rows = 2 halves of 16; K-fragments and V-fragments are
// read from LDS ONCE per tile and reused for both halves (per-q LDS traffic
// -40%). P single-buffered per wave (in-order DS ops make overwrite safe).
// Q pre-scaled by 1/8*log2e; row-sum via mfma(P, ones).
__global__ __launch_bounds__(512, 2) void k_attn(const short* __restrict__ Q,
                                                 const short* __restrict__ Kt,
                                                 const short* __restrict__ VT,
                                                 short* __restrict__ O) {
    __shared__ short Kl[2][64 * 64];   // [buf][kv_local][dk-chunk swz]
    __shared__ short Vl[2][64 * 64];   // [buf][dk][t-chunk swz]
    __shared__ short Pl[8][16 * 64];   // per-wave [q=l16][kv granule-swz]
    const int bh = blockIdx.x;
    const int qb = blockIdx.y;
    const int t = threadIdx.x;
    const int w = t >> 6, l = t & 63;
    const int l16 = l & 15, lg = l >> 4;
    const int sw = l16 & 7;                       // K/V chunk XOR
    const int pmask = (l16 & 7) << 1;             // P 8B-granule XOR (even)
    const int srow = l >> 3;
    const int scol = ((l & 7) ^ srow) * 8;        // pre-swizzled global col

    // wave w owns q rows qb*256 + w*32 + qh*16 + l16
    const short* Qb0 = Q + ((size_t)bh * 1024 + qb * 256 + w * 32 + l16) * 64 + lg * 8;
    bf16x8 qf[2][2];
    qf[0][0] = *(const bf16x8*)Qb0;
    qf[0][1] = *(const bf16x8*)(Qb0 + 32);
    qf[1][0] = *(const bf16x8*)(Qb0 + 16 * 64);
    qf[1][1] = *(const bf16x8*)(Qb0 + 16 * 64 + 32);

    const short* Kbase = Kt + (size_t)bh * (1024 * 64);
    const short* Vbase = VT + (size_t)bh * (64 * 1024);

    const float THR = 11.5415603f;    // 8 nats in log2

    bf16x8 ones;
#pragma unroll
    for (int i = 0; i < 8; ++i) ones[i] = (short)0x3F80;  // bf16 1.0

    float m[2] = {-1e30f, -1e30f};    // per-lane running max, per half
    f32x4 oacc[2][4] = {};
    f32x4 oaccS[2] = {};              // row-sum accumulators (P x ones)

    // wave w stages K rows [w*8,+8) and V rows [w*8,+8): 2 GLD16 per tile
    auto stage = [&](int buf, int t0) {
        int roww = w * 8;
        GLD16(Kbase + (size_t)(t0 + roww + srow) * 64 + scol,
              &Kl[buf][roww * 64]);
        GLD16(Vbase + (size_t)(roww + srow) * 1024 + t0 + scol,
              &Vl[buf][roww * 64]);
    };

    // softmax for one 16-q half: updates m[h], rescales oacc[h]/oaccS[h]
    auto softmax = [&](f32x4 (&s)[4], int h) {
        float m1 = fmaxf(fmaxf(s[0][0], s[0][1]), s[0][2]);
        float m2 = fmaxf(fmaxf(s[0][3], s[1][0]), s[1][1]);
        float m3 = fmaxf(fmaxf(s[1][2], s[1][3]), s[2][0]);
        float m4 = fmaxf(fmaxf(s[2][1], s[2][2]), s[2][3]);
        float m5 = fmaxf(fmaxf(s[3][0], s[3][1]), s[3][2]);
        float mx = fmaxf(fmaxf(m1, m2), m3);
        mx = fmaxf(fmaxf(m4, m5), fmaxf(mx, s[3][3]));
        mx = fmaxf(mx, __shfl_xor(mx, 16));
        mx = fmaxf(mx, __shfl_xor(mx, 32));
        if (__any(mx > m[h] + THR)) {
            float mn = fmaxf(m[h], mx);
            float al = exp2f(m[h] - mn);
            m[h] = mn;
#pragma unroll
            for (int n = 0; n < 4; ++n)
#pragma unroll
                for (int r = 0; r < 4; ++r) s[n][r] = exp2f(s[n][r] - mn);
#pragma unroll
            for (int r = 0; r < 4; ++r) {
                float alr = __shfl(al, lg * 4 + r);   // al for q-row lg*4+r
                oaccS[h][r] *= alr;
#pragma unroll
                for (int n = 0; n < 4; ++n) oacc[h][n][r] *= alr;
            }
        } else {   // T13 defer: keep m, skip rescale (P bounded by 2^THR)
#pragma unroll
            for (int n = 0; n < 4; ++n)
#pragma unroll
                for (int r = 0; r < 4; ++r) s[n][r] = exp2f(s[n][r] - m[h]);
        }
    };

    auto pwrite = [&](const f32x4 (&s)[4]) {
#pragma unroll
        for (int n = 0; n < 4; ++n) {
            uint2v pv;
            pv[0] = cvtpk(s[n][0], s[n][1]);
            pv[1] = cvtpk(s[n][2], s[n][3]);
            int g = (n * 4 + lg) ^ pmask;
            *(uint2v*)((char*)Pl[w] + l16 * 128 + g * 8) = pv;
        }
    };

    auto compute = [&](int cur) {
        // K fragments: read once, used by both q-halves
        bf16x8 kf[4][2];
#pragma unroll
        for (int n = 0; n < 4; ++n) {
            kf[n][0] = *(const bf16x8*)&Kl[cur][(n * 16 + l16) * 64 + (lg ^ sw) * 8];
            kf[n][1] = *(const bf16x8*)&Kl[cur][(n * 16 + l16) * 64 + ((4 + lg) ^ sw) * 8];
        }
        f32x4 s0[4], s1[4];
#pragma unroll
        for (int n = 0; n < 4; ++n) {
            f32x4 a = {0.f, 0.f, 0.f, 0.f};
            a = __builtin_amdgcn_mfma_f32_16x16x32_bf16(kf[n][0], qf[0][0], a, 0, 0, 0);
            a = __builtin_amdgcn_mfma_f32_16x16x32_bf16(kf[n][1], qf[0][1], a, 0, 0, 0);
            s0[n] = a;
        }
#pragma unroll
        for (int n = 0; n < 4; ++n) {
            f32x4 a = {0.f, 0.f, 0.f, 0.f};
            a = __builtin_amdgcn_mfma_f32_16x16x32_bf16(kf[n][0], qf[1][0], a, 0, 0, 0);
            a = __builtin_amdgcn_mfma_f32_16x16x32_bf16(kf[n][1], qf[1][1], a, 0, 0, 0);
            s1[n] = a;
        }
        softmax(s0, 0);
        softmax(s1, 1);
        // V fragments: read once, used by both q-halves
        bf16x8 vb[2][4];
#pragma unroll
        for (int kk = 0; kk < 2; ++kk)
#pragma unroll
            for (int n = 0; n < 4; ++n)
                vb[kk][n] = *(const bf16x8*)&Vl[cur][(n * 16 + l16) * 64 +
                                                     ((kk * 4 + lg) ^ sw) * 8];
        // half 0: P write, PV
        pwrite(s0);
#pragma unroll
        for (int kk = 0; kk < 2; ++kk) {
            int gp = (8 * kk + 2 * lg) ^ pmask;
            bf16x8 pa = *(const bf16x8*)((const char*)Pl[w] + l16 * 128 + gp * 8);
            oaccS[0] = __builtin_amdgcn_mfma_f32_16x16x32_bf16(pa, ones, oaccS[0], 0, 0, 0);
#pragma unroll
            for (int n = 0; n < 4; ++n)
                oacc[0][n] = __builtin_amdgcn_mfma_f32_16x16x32_bf16(pa, vb[kk][n], oacc[0][n], 0, 0, 0);
        }
        // half 1: overwrite P (per-wave DS ops are in-order; h0 pa reads done)
        pwrite(s1);
#pragma unroll
        for (int kk = 0; kk < 2; ++kk) {
            int gp = (8 * kk + 2 * lg) ^ pmask;
            bf16x8 pa = *(const bf16x8*)((const char*)Pl[w] + l16 * 128 + gp * 8);
            oaccS[1] = __builtin_amdgcn_mfma_f32_16x16x32_bf16(pa, ones, oaccS[1], 0, 0, 0);
#pragma unroll
            for (int n = 0; n < 4; ++n)
                oacc[1][n] = __builtin_amdgcn_mfma_f32_16x16x32_bf16(pa, vb[kk][n], oacc[1][n], 0, 0, 0);
        }
    };

    stage(0, 0);
    for (int ti = 0; ti < 15; ++ti) {
        int cur = ti & 1;
        stage(cur ^ 1, (ti + 1) * 64);
        WAITV(2);   // my 2 loads for buf[cur] landed; next-tile 2 in flight
        SBAR();
        compute(cur);
        SBAR();
    }
    WAITV(0);
    SBAR();
    compute(1);

    const int b = bh >> 4, h = bh & 15;
#pragma unroll
    for (int qh = 0; qh < 2; ++qh)
#pragma unroll
        for (int r = 0; r < 4; ++r) {
            float inv = 1.f / oaccS[qh][r];   // denom for q-row lg*4+r
            size_t row = (size_t)(b * 1024 + qb * 256 + w * 32 + qh * 16 +
                                  lg * 4 + r);
#pragma unroll
            for (int n = 0; n < 4; ++n)
                O[row * 1024 + h * 64 + n * 16 + l16] = f2bf(oacc[qh][n][r] * inv);
        }
}

// ---- Wo split-K reduce (3+1 bf16 partials) + bo + src resid -> LN1 --------
// emits xf (f32, final-residual) and xbf (bf16, FFN-up input)
__global__ __launch_bounds__(256) void k_lnwo(const short* __restrict__ p012,
                                              const short* __restrict__ p3,
                                              const float* __restrict__ bias,
                                              const float* __restrict__ resid,
                                              const float* __restrict__ g,
                                              const float* __restrict__ be,
                                              float* __restrict__ of,
                                              short* __restrict__ ob) {
    const int row = blockIdx.x, t = threadIdx.x;
    float4 x = ((const float4*)(resid + ((size_t)row << 10)))[t];
    float4 bv = ((const float4*)bias)[t];
    x.x += bv.x; x.y += bv.y; x.z += bv.z; x.w += bv.w;
#pragma unroll
    for (int kz = 0; kz < 3; ++kz) {
        short4v p = ((const short4v*)(p012 + (((size_t)kz * 4096 + row) << 10)))[t];
        x.x += bf2f(p[0]); x.y += bf2f(p[1]); x.z += bf2f(p[2]); x.w += bf2f(p[3]);
    }
    {
        short4v p = ((const short4v*)(p3 + ((size_t)row << 10)))[t];
        x.x += bf2f(p[0]); x.y += bf2f(p[1]); x.z += bf2f(p[2]); x.w += bf2f(p[3]);
    }
    float s = x.x + x.y + x.z + x.w;
    float s2 = x.x * x.x + x.y * x.y + x.z * x.z + x.w * x.w;
#pragma unroll
    for (int mm = 1; mm < 64; mm <<= 1) {
        s += __shfl_xor(s, mm);
        s2 += __shfl_xor(s2, mm);
    }
    __shared__ float red[8];
    if ((t & 63) == 0) { red[t >> 6] = s; red[4 + (t >> 6)] = s2; }
    __syncthreads();
    s = red[0] + red[1] + red[2] + red[3];
    s2 = red[4] + red[5] + red[6] + red[7];
    float mean = s * (1.f / 1024.f);
    float var = s2 * (1.f / 1024.f) - mean * mean;
    float rstd = rsqrtf(var + 1e-5f);
    int c = t * 4;
    float4 y;
    y.x = (x.x - mean) * rstd * g[c + 0] + be[c + 0];
    y.y = (x.y - mean) * rstd * g[c + 1] + be[c + 1];
    y.z = (x.z - mean) * rstd * g[c + 2] + be[c + 2];
    y.w = (x.w - mean) * rstd * g[c + 3] + be[c + 3];
    ((float4*)(of + ((size_t)row << 10)))[t] = y;
    short4v o;
    o[0] = f2bf(y.x); o[1] = f2bf(y.y); o[2] = f2bf(y.z); o[3] = f2bf(y.w);
    ((short4v*)(ob + ((size_t)row << 10)))[t] = o;
}

// ---- split-K reduce (4 contiguous bf16 partials) + bias + resid -> LN2 ----
__global__ __launch_bounds__(256) void k_lnred(const short* __restrict__ part,
                                               const float* __restrict__ bias,
                                               const float* __restrict__ resid,
                                               const float* __restrict__ g,
                                               const float* __restrict__ be,
                                               float* __restrict__ of) {
    const int row = blockIdx.x, t = threadIdx.x;
    float4 x = ((const float4*)(resid + ((size_t)row << 10)))[t];
    float4 bv = ((const float4*)bias)[t];
    x.x += bv.x; x.y += bv.y; x.z += bv.z; x.w += bv.w;
#pragma unroll
    for (int kz = 0; kz < 4; ++kz) {
        short4v p = ((const short4v*)(part + (((size_t)kz * 4096 + row) << 10)))[t];
        x.x += bf2f(p[0]); x.y += bf2f(p[1]); x.z += bf2f(p[2]); x.w += bf2f(p[3]);
    }
    float s = x.x + x.y + x.z + x.w;
    float s2 = x.x * x.x + x.y * x.y + x.z * x.z + x.w * x.w;
#pragma unroll
    for (int mm = 1; mm < 64; mm <<= 1) {
        s += __shfl_xor(s, mm);
        s2 += __shfl_xor(s2, mm);
    }
    __shared__ float red[8];
    if ((t & 63) == 0) { red[t >> 6] = s; red[4 + (t >> 6)] = s2; }
    __syncthreads();
    s = red[0] + red[1] + red[2] + red[3];
    s2 = red[4] + red[5] + red[6] + red[7];
    float mean = s * (1.f / 1024.f);
    float var = s2 * (1.f / 1024.f) - mean * mean;
    float rstd = rsqrtf(var + 1e-5f);
    int c = t * 4;
    float4 y;
    y.x = (x.x - mean) * rstd * g[c + 0] + be[c + 0];
    y.y = (x.y - mean) * rstd * g[c + 1] + be[c + 1];
    y.z = (x.z - mean) * rstd * g[c + 2] + be[c + 2];
    y.w = (x.w - mean) * rstd * g[c + 3] + be[c + 3];
    ((float4*)(of + ((size_t)row << 10)))[t] = y;
}

// ---------------- host ----------------
extern "C" void kernel_launch(void* const* d_in, const int* in_sizes, int n_in,
                              void* d_out, int out_size, void* d_ws, size_t ws_size,
                              hipStream_t stream) {
    (void)in_sizes; (void)n_in; (void)out_size; (void)ws_size;
    const float* src = (const float*)d_in[0];
    const float* Wq  = (const float*)d_in[1];
    const float* bq  = (const float*)d_in[2];
    const float* Wk  = (const float*)d_in[3];
    const float* bk  = (const float*)d_in[4];
    const float* Wv  = (const float*)d_in[5];
    const float* bv  = (const float*)d_in[6];
    const float* Wo  = (const float*)d_in[7];
    const float* bo  = (const float*)d_in[8];
    const float* g1  = (const float*)d_in[9];
    const float* be1 = (const float*)d_in[10];
    const float* W1  = (const float*)d_in[11];
    const float* b1  = (const float*)d_in[12];
    const float* W2  = (const float*)d_in[13];
    const float* b2  = (const float*)d_in[14];
    const float* g2  = (const float*)d_in[15];
    const float* be2 = (const float*)d_in[16];

    char* ws = (char*)d_ws;
    const size_t MB = 1048576;
    short* srcbf  = (short*)(ws + 0);
    short* Qb     = (short*)(ws + 8 * MB);
    short* Kb     = (short*)(ws + 16 * MB);
    short* VTb    = (short*)(ws + 24 * MB);
    short* h1     = (short*)(ws + 0);
    short* Obuf   = srcbf;
    short* W2T    = (short*)(ws + 32 * MB);
    float* xf     = (float*)(ws + 40 * MB);
    short* WqkvT  = (short*)(ws + 56 * MB);
    short* WoT    = (short*)(ws + 62 * MB);
    short* W1T    = (short*)(ws + 64 * MB);
    short* partWo0 = (short*)(ws + 8 * MB);   // Wo slices 0-2 (24MB)
    short* partWo3 = (short*)(ws + 72 * MB);  // Wo slice 3 (8MB)
    short* xbf    = (short*)(ws + 88 * MB);
    short* part   = (short*)(ws + 56 * MB);   // FFN-down [4][4096][1024] bf16

    // prep (all coalesced tiled transposes)
    k_cast<<<4096, 256, 0, stream>>>(src, srcbf, 1048576);
    k_tr3<<<dim3(1, 16, 48), 256, 0, stream>>>(Wq, Wk, Wv, WqkvT);
    k_tr<<<dim3(16, 16, 1), 256, 0, stream>>>(Wo, WoT, 1024, 1024, 0, 0);
    k_tr<<<dim3(64, 16, 1), 256, 0, stream>>>(W1, W1T, 1024, 4096, 0, 0);
    k_tr<<<dim3(16, 64, 1), 256, 0, stream>>>(W2, W2T, 4096, 1024, 0, 0);
    // QKV projection (M=4096, N=3072, K=1024)
    k_gemm8<0><<<dim3(12, 16, 1), 512, 0, stream>>>(srcbf, WqkvT, 1024, 16,
                                                    bq, bk, bv, Qb, Kb, VTb);
    // attention (8 waves, 256 q-rows per block)
    k_attn<<<dim3(64, 4), 512, 0, stream>>>(Qb, Kb, VTb, Obuf);
    // output projection (M=4096, N=1024, K=1024) -- split-K=4, NT=4
    k_gemm8<3><<<dim3(4, 16, 4), 512, 0, stream>>>(Obuf, WoT, 1024, 4,
                                                   nullptr, nullptr, nullptr,
                                                   partWo0, partWo3, nullptr);
    // reduce Wo partials + bo + src residual -> LN1 -> xf (f32) + xbf (bf16)
    k_lnwo<<<4096, 256, 0, stream>>>(partWo0, partWo3, bo, src, g1, be1, xf, xbf);
    // FFN up + relu (M=4096, N=4096, K=1024)
    k_gemm8<2><<<dim3(16, 16, 1), 512, 0, stream>>>(xbf, W1T, 1024, 16,
                                                    b1, nullptr, nullptr,
                                                    h1, nullptr, nullptr);
    // FFN down (M=4096, N=1024, K=4096) -- split-K=4, NT=16
    k_gemm8<3><<<dim3(4, 16, 4), 512, 0, stream>>>(h1, W2T, 4096, 16,
                                                   nullptr, nullptr, nullptr,
                                                   part, part + 3u * 4194304u,
                                                   nullptr);
    // reduce partials + b2 + xf residual -> LayerNorm2 -> d_out
    k_lnred<<<4096, 256, 0, stream>>>(part, b2, xf, g2, be2, (float*)d_out);
}

// Round 14
// 316.479 us; speedup vs baseline: 1.1457x; 1.1457x over previous
//
#include <hip/hip_runtime.h>
#include <hip/hip_bf16.h>

#define DEV __device__ __forceinline__

typedef __attribute__((ext_vector_type(8))) short bf16x8;
typedef __attribute__((ext_vector_type(4))) float f32x4;
typedef __attribute__((ext_vector_type(4))) short short4v;
typedef __attribute__((ext_vector_type(2))) unsigned uint2v;

DEV short f2bf(float f) {
    union { float f; unsigned u; } x; x.f = f;
    unsigned u = x.u;
    unsigned r = (u + 0x7fffu + ((u >> 16) & 1u)) >> 16;
    return (short)r;
}

DEV float bf2f(short s) {
    union { unsigned u; float f; } x;
    x.u = ((unsigned)(unsigned short)s) << 16;
    return x.f;
}

// pack 2 f32 -> 2 bf16 in one u32 (lo = a, hi = b)
DEV unsigned cvtpk(float a, float b) {
    unsigned r;
    asm("v_cvt_pk_bf16_f32 %0, %1, %2" : "=v"(r) : "v"(a), "v"(b));
    return r;
}

// async global->LDS, 16B per lane; LDS dest = wave-uniform base + lane*16
#define GLD16(g, l)                                                         \
    __builtin_amdgcn_global_load_lds(                                       \
        (const __attribute__((address_space(1))) void*)(g),                 \
        (__attribute__((address_space(3))) void*)(l), 16, 0, 0)

#define WAITV(n) asm volatile("s_waitcnt vmcnt(" #n ")" ::: "memory")
#define SBAR()   asm volatile("s_barrier" ::: "memory")
#define LGKMDRAIN() asm volatile("s_waitcnt lgkmcnt(0)" ::: "memory")

// ---------------- prep kernels ----------------

__global__ __launch_bounds__(256) void k_cast(const float* __restrict__ in,
                                              short* __restrict__ out, int n4) {
    int i = blockIdx.x * 256 + threadIdx.x;
    if (i >= n4) return;
    float4 v = ((const float4*)in)[i];
    short4v o;
    o[0] = f2bf(v.x); o[1] = f2bf(v.y); o[2] = f2bf(v.z); o[3] = f2bf(v.w);
    ((short4v*)out)[i] = o;
}

// tiled transpose+cast: out[(c)*R + r] = bf16(in[r*C + c]); R,C multiples of 64
__global__ __launch_bounds__(256) void k_tr(const float* __restrict__ in,
                                            short* __restrict__ out,
                                            int R, int C,
                                            long in_hs, long out_hs) {
    in  += (size_t)blockIdx.z * in_hs;
    out += (size_t)blockIdx.z * out_hs;
    __shared__ short tile[64][68];
    const int t = threadIdx.x;
    const int r0 = blockIdx.y * 64, c0 = blockIdx.x * 64;
    const int lr = t >> 4, lc4 = (t & 15) * 4;
#pragma unroll
    for (int it = 0; it < 4; ++it) {
        int r = lr + it * 16;
        float4 v = *(const float4*)(in + (size_t)(r0 + r) * C + c0 + lc4);
        tile[lc4 + 0][r] = f2bf(v.x);
        tile[lc4 + 1][r] = f2bf(v.y);
        tile[lc4 + 2][r] = f2bf(v.z);
        tile[lc4 + 3][r] = f2bf(v.w);
    }
    __syncthreads();
#pragma unroll
    for (int it = 0; it < 4; ++it) {
        int c = lr + it * 16;
        short4v o;
        o[0] = tile[c][lc4 + 0];
        o[1] = tile[c][lc4 + 1];
        o[2] = tile[c][lc4 + 2];
        o[3] = tile[c][lc4 + 3];
        *(short4v*)(out + (size_t)(c0 + c) * R + r0 + lc4) = o;
    }
}

// merged QKV per-head transpose: z in [0,48): p=z/16 selects Wq/Wk/Wv,
// h=z%16 the head. R=1024, C=64. out laid [p][h][64 k][1024 d].
__global__ __launch_bounds__(256) void k_tr3(const float* __restrict__ Wq,
                                             const float* __restrict__ Wk,
                                             const float* __restrict__ Wv,
                                             short* __restrict__ out) {
    const int z = blockIdx.z;
    const float* in = ((z < 16) ? Wq : (z < 32) ? Wk : Wv) +
                      (size_t)(z & 15) * 65536;
    short* o = out + (size_t)z * 65536;
    __shared__ short tile[64][68];
    const int t = threadIdx.x;
    const int r0 = blockIdx.y * 64;
    const int lr = t >> 4, lc4 = (t & 15) * 4;
#pragma unroll
    for (int it = 0; it < 4; ++it) {
        int r = lr + it * 16;
        float4 v = *(const float4*)(in + (size_t)(r0 + r) * 64 + lc4);
        tile[lc4 + 0][r] = f2bf(v.x);
        tile[lc4 + 1][r] = f2bf(v.y);
        tile[lc4 + 2][r] = f2bf(v.z);
        tile[lc4 + 3][r] = f2bf(v.w);
    }
    __syncthreads();
#pragma unroll
    for (int it = 0; it < 4; ++it) {
        int c = lr + it * 16;
        short4v ov;
        ov[0] = tile[c][lc4 + 0];
        ov[1] = tile[c][lc4 + 1];
        ov[2] = tile[c][lc4 + 2];
        ov[3] = tile[c][lc4 + 3];
        *(short4v*)(o + (size_t)c * 1024 + r0 + lc4) = ov;
    }
}

// ======== 256x256 GEMM, 2-barrier K-loop (R12, measured = R9) ===============
// C = A[M,K] * BT[N,K]^T. 512 thr = 8 waves (2M x 4N), wave tile 128x64, BK=64.
// blockIdx.z = split-K slice over K range [z*NT*64, (z+1)*NT*64).
// MODE 0: QKV scatter epilogue (Q pre-scaled by 1/8*log2e);
// MODE 2: bf16 relu(acc+bias);
// MODE 3: bf16 split-K partial -- slices 0..2 -> o0 + z*M*N, slice 3 -> o1
template <int MODE>
__global__ __launch_bounds__(512, 2) void k_gemm8(
    const short* __restrict__ A, const short* __restrict__ BT,
    int K, int NT,
    const float* __restrict__ f0, const float* __restrict__ f1,
    const float* __restrict__ f2,
    void* __restrict__ o0, void* __restrict__ o1, void* __restrict__ o2) {
    __shared__ short lds[2][2][2][128 * 64];   // [buf][op A=0,B=1][half][r*64+c]
    const int t = threadIdx.x;
    const int w = t >> 6, l = t & 63;
    const int l16 = l & 15, lg = l >> 4;
    const int wm = w >> 2, wn = w & 3;
    const int bn = blockIdx.x, bm = blockIdx.y;
    const int koff = blockIdx.z * NT * 64;
    const short* Ab = A + (size_t)bm * 256 * K + koff;
    const short* Bb = BT + (size_t)bn * 256 * K + koff;
    const int srow = l >> 3;                    // staging row within 8-row group
    const int scol = ((l & 7) ^ srow) * 8;      // pre-swizzled source col (shorts)
    const int offk0 = ((0 + lg) ^ (l16 & 7)) * 8;  // swizzled ds_read chunk, kk=0
    const int offk1 = ((4 + lg) ^ (l16 & 7)) * 8;  // kk=1

    f32x4 acc[8][4] = {};

    auto stg = [&](int buf, int op, int h, int kt) {
#pragma unroll
        for (int i = 0; i < 2; ++i) {
            int row = h * 128 + w * 16 + i * 8 + srow;
            GLD16((op ? Bb : Ab) + (size_t)row * K + (size_t)kt * 64 + scol,
                  &lds[buf][op][h][(w * 16 + i * 8) * 64]);
        }
    };

    // prologue: A(0),B(0)->buf0 (8 loads); B(t1)->buf1 (4 loads)
    stg(0, 0, 0, 0); stg(0, 0, 1, 0);
    stg(0, 1, 0, 0); stg(0, 1, 1, 0);
    const int t1p = (NT > 1) ? 1 : 0;
    stg(1, 1, 0, t1p); stg(1, 1, 1, t1p);
    WAITV(4);   // tile0 landed; B(t1) 4 loads in flight
    SBAR();

    for (int kt = 0; kt < NT; ++kt) {
        const int cur = kt & 1, nxt = cur ^ 1;
        const int t1 = (kt + 1 < NT) ? kt + 1 : NT - 1;
        const int t2 = (kt + 2 < NT) ? kt + 2 : NT - 1;

        // early stage: A(t1)->nxt (no reader conflict; hides under compute)
        stg(nxt, 0, 0, t1); stg(nxt, 0, 1, t1);

        bf16x8 a0[4][2], a1[4][2], b0[2][2], b1[2][2];
#pragma unroll
        for (int m = 0; m < 4; ++m) {
            a0[m][0] = *(const bf16x8*)&lds[cur][0][wm][(m * 16 + l16) * 64 + offk0];
            a0[m][1] = *(const bf16x8*)&lds[cur][0][wm][(m * 16 + l16) * 64 + offk1];
        }
#pragma unroll
        for (int n = 0; n < 2; ++n) {
            int r = (wn & 1) * 64 + n * 16 + l16;
            b0[n][0] = *(const bf16x8*)&lds[cur][1][wn >> 1][r * 64 + offk0];
            b0[n][1] = *(const bf16x8*)&lds[cur][1][wn >> 1][r * 64 + offk1];
            int r2 = (wn & 1) * 64 + (n + 2) * 16 + l16;
            b1[n][0] = *(const bf16x8*)&lds[cur][1][wn >> 1][r2 * 64 + offk0];
            b1[n][1] = *(const bf16x8*)&lds[cur][1][wn >> 1][r2 * 64 + offk1];
        }
        __builtin_amdgcn_s_setprio(1);
#pragma unroll
        for (int m = 0; m < 4; ++m)
#pragma unroll
            for (int n = 0; n < 2; ++n) {
                acc[m][n] = __builtin_amdgcn_mfma_f32_16x16x32_bf16(a0[m][0], b0[n][0], acc[m][n], 0, 0, 0);
                acc[m][n] = __builtin_amdgcn_mfma_f32_16x16x32_bf16(a0[m][1], b0[n][1], acc[m][n], 0, 0, 0);
                acc[m][n + 2] = __builtin_amdgcn_mfma_f32_16x16x32_bf16(a0[m][0], b1[n][0], acc[m][n + 2], 0, 0, 0);
                acc[m][n + 2] = __builtin_amdgcn_mfma_f32_16x16x32_bf16(a0[m][1], b1[n][1], acc[m][n + 2], 0, 0, 0);
            }
        __builtin_amdgcn_s_setprio(0);
#pragma unroll
        for (int m = 0; m < 4; ++m) {
            a1[m][0] = *(const bf16x8*)&lds[cur][0][wm][((m + 4) * 16 + l16) * 64 + offk0];
            a1[m][1] = *(const bf16x8*)&lds[cur][0][wm][((m + 4) * 16 + l16) * 64 + offk1];
        }
        __builtin_amdgcn_s_setprio(1);
#pragma unroll
        for (int m = 0; m < 4; ++m)
#pragma unroll
            for (int n = 0; n < 2; ++n) {
                acc[m + 4][n + 2] = __builtin_amdgcn_mfma_f32_16x16x32_bf16(a1[m][0], b1[n][0], acc[m + 4][n + 2], 0, 0, 0);
                acc[m + 4][n + 2] = __builtin_amdgcn_mfma_f32_16x16x32_bf16(a1[m][1], b1[n][1], acc[m + 4][n + 2], 0, 0, 0);
                acc[m + 4][n] = __builtin_amdgcn_mfma_f32_16x16x32_bf16(a1[m][0], b0[n][0], acc[m + 4][n], 0, 0, 0);
                acc[m + 4][n] = __builtin_amdgcn_mfma_f32_16x16x32_bf16(a1[m][1], b0[n][1], acc[m + 4][n], 0, 0, 0);
            }
        __builtin_amdgcn_s_setprio(0);

        LGKMDRAIN();   // all cur reads retired in this wave
        SBAR();        // ... in every wave -> safe to overwrite cur-B
        stg(cur, 1, 0, t2); stg(cur, 1, 1, t2);   // B(t2)->cur (4 loads)
        WAITV(4);      // A(t1),B(t1) retired; only B(t2)'s 4 in flight
        SBAR();        // all waves -> t1 fully in LDS
    }
    WAITV(0);          // retire clamped trailing stages before exit

    const int N = gridDim.x * 256;
#pragma unroll
    for (int m = 0; m < 8; ++m) {
        int rowbase = bm * 256 + wm * 128 + m * 16 + lg * 4;
#pragma unroll
        for (int n = 0; n < 4; ++n) {
            int col = bn * 256 + wn * 64 + n * 16 + l16;
            if constexpr (MODE == 0) {
                int p = col >> 10, c1 = col & 1023;
                int hh = c1 >> 6, dk = c1 & 63;
                const float* bias = (p == 0) ? f0 : (p == 1) ? f1 : f2;
                float bvl = bias[c1];
                // fold softmax scale*log2e into Q
                float qs = (p == 0) ? 0.18033688011112042f : 1.0f;
                int b = rowbase >> 10, s = rowbase & 1023;
                if (p == 2) {
                    short4v vv;
#pragma unroll
                    for (int rr = 0; rr < 4; ++rr) vv[rr] = f2bf(acc[m][n][rr] + bvl);
                    *(short4v*)((short*)o2 + (((size_t)(b * 16 + hh) * 64 + dk) << 10) + s) = vv;
                } else {
                    short* dst = (p == 0) ? (short*)o0 : (short*)o1;
#pragma unroll
                    for (int rr = 0; rr < 4; ++rr)
                        dst[(((size_t)(b * 16 + hh) << 10) + s + rr) * 64 + dk] =
                            f2bf((acc[m][n][rr] + bvl) * qs);
                }
            } else if constexpr (MODE == 2) {
                float bvl = f0[col];
#pragma unroll
                for (int rr = 0; rr < 4; ++rr) {
                    size_t idx = (size_t)(rowbase + rr) * N + col;
                    float y = acc[m][n][rr] + bvl;
                    ((short*)o0)[idx] = f2bf(y > 0.f ? y : 0.f);
                }
            } else {  // MODE 3: bf16 split-K partial; z<3 -> o0+z*M*N, z=3 -> o1
                const int Mtot = gridDim.y * 256;
                short* dst = (blockIdx.z < 3)
                    ? (short*)o0 + (size_t)blockIdx.z * Mtot * N
                    : (short*)o1;
                size_t base = (size_t)rowbase * N + col;
#pragma unroll
                for (int rr = 0; rr < 4; ++rr)
                    dst[base + (size_t)rr * N] = f2bf(acc[m][n][rr]);
            }
        }
    }
}

// ------- flash attention R14: QBLK=256, rule-#20-safe (named per-half state) -
// grid (64, 4). Each wave owns 32 q rows = 2 halves of 16; K/V fragments read
// from LDS ONCE per tile, reused for both halves. P single-buffered per wave.
// All per-half state in NAMED registers (no runtime-indexed arrays -> no
// scratch; R13's 487MB WRITE_SIZE bug). Q pre-scaled by 1/8*log2e.
__global__ __launch_bounds__(512, 2) void k_attn(const short* __restrict__ Q,
                                                 const short* __restrict__ Kt,
                                                 const short* __restrict__ VT,
                                                 short* __restrict__ O) {
    __shared__ short Kl[2][64 * 64];   // [buf][kv_local][dk-chunk swz]
    __shared__ short Vl[2][64 * 64];   // [buf][dk][t-chunk swz]
    __shared__ short Pl[8][16 * 64];   // per-wave [q=l16][kv granule-swz]
    const int bh = blockIdx.x;
    const int qb = blockIdx.y;
    const int t = threadIdx.x;
    const int w = t >> 6, l = t & 63;
    const int l16 = l & 15, lg = l >> 4;
    const int sw = l16 & 7;                       // K/V chunk XOR
    const int pmask = (l16 & 7) << 1;             // P 8B-granule XOR (even)
    const int srow = l >> 3;
    const int scol = ((l & 7) ^ srow) * 8;        // pre-swizzled global col

    // wave w owns q rows qb*256 + w*32 + {0,16} + l16
    const short* Qb0 = Q + ((size_t)bh * 1024 + qb * 256 + w * 32 + l16) * 64 + lg * 8;
    bf16x8 qf0a = *(const bf16x8*)Qb0;
    bf16x8 qf0b = *(const bf16x8*)(Qb0 + 32);
    bf16x8 qf1a = *(const bf16x8*)(Qb0 + 16 * 64);
    bf16x8 qf1b = *(const bf16x8*)(Qb0 + 16 * 64 + 32);

    const short* Kbase = Kt + (size_t)bh * (1024 * 64);
    const short* Vbase = VT + (size_t)bh * (64 * 1024);

    const float THR = 11.5415603f;    // 8 nats in log2

    bf16x8 ones;
#pragma unroll
    for (int i = 0; i < 8; ++i) ones[i] = (short)0x3F80;  // bf16 1.0

    // NAMED per-half state (rule #20: no runtime-indexed arrays)
    float m0 = -1e30f, m1 = -1e30f;
    f32x4 oacc0[4] = {}, oacc1[4] = {};
    f32x4 oaccS0 = {}, oaccS1 = {};

    // wave w stages K rows [w*8,+8) and V rows [w*8,+8): 2 GLD16 per tile
    auto stage = [&](int buf, int t0) {
        int roww = w * 8;
        GLD16(Kbase + (size_t)(t0 + roww + srow) * 64 + scol,
              &Kl[buf][roww * 64]);
        GLD16(Vbase + (size_t)(roww + srow) * 1024 + t0 + scol,
              &Vl[buf][roww * 64]);
    };

    // softmax for one 16-q half; all state via references to NAMED objects
    auto softmax = [&](f32x4 (&s)[4], float& mh, f32x4 (&oh)[4], f32x4& osh) {
        float m1_ = fmaxf(fmaxf(s[0][0], s[0][1]), s[0][2]);
        float m2_ = fmaxf(fmaxf(s[0][3], s[1][0]), s[1][1]);
        float m3_ = fmaxf(fmaxf(s[1][2], s[1][3]), s[2][0]);
        float m4_ = fmaxf(fmaxf(s[2][1], s[2][2]), s[2][3]);
        float m5_ = fmaxf(fmaxf(s[3][0], s[3][1]), s[3][2]);
        float mx = fmaxf(fmaxf(m1_, m2_), m3_);
        mx = fmaxf(fmaxf(m4_, m5_), fmaxf(mx, s[3][3]));
        mx = fmaxf(mx, __shfl_xor(mx, 16));
        mx = fmaxf(mx, __shfl_xor(mx, 32));
        if (__any(mx > mh + THR)) {
            float mn = fmaxf(mh, mx);
            float al = exp2f(mh - mn);
            mh = mn;
#pragma unroll
            for (int n = 0; n < 4; ++n)
#pragma unroll
                for (int r = 0; r < 4; ++r) s[n][r] = exp2f(s[n][r] - mn);
#pragma unroll
            for (int r = 0; r < 4; ++r) {
                float alr = __shfl(al, lg * 4 + r);   // al for q-row lg*4+r
                osh[r] *= alr;
#pragma unroll
                for (int n = 0; n < 4; ++n) oh[n][r] *= alr;
            }
        } else {   // T13 defer: keep m, skip rescale (P bounded by 2^THR)
#pragma unroll
            for (int n = 0; n < 4; ++n)
#pragma unroll
                for (int r = 0; r < 4; ++r) s[n][r] = exp2f(s[n][r] - mh);
        }
    };

    auto pwrite = [&](const f32x4 (&s)[4]) {
#pragma unroll
        for (int n = 0; n < 4; ++n) {
            uint2v pv;
            pv[0] = cvtpk(s[n][0], s[n][1]);
            pv[1] = cvtpk(s[n][2], s[n][3]);
            int g = (n * 4 + lg) ^ pmask;
            *(uint2v*)((char*)Pl[w] + l16 * 128 + g * 8) = pv;
        }
    };

    auto compute = [&](int cur) {
        // K fragments: read once, used by both q-halves
        bf16x8 kf[4][2];
#pragma unroll
        for (int n = 0; n < 4; ++n) {
            kf[n][0] = *(const bf16x8*)&Kl[cur][(n * 16 + l16) * 64 + (lg ^ sw) * 8];
            kf[n][1] = *(const bf16x8*)&Kl[cur][(n * 16 + l16) * 64 + ((4 + lg) ^ sw) * 8];
        }
        f32x4 s0[4], s1[4];
#pragma unroll
        for (int n = 0; n < 4; ++n) {
            f32x4 a = {0.f, 0.f, 0.f, 0.f};
            a = __builtin_amdgcn_mfma_f32_16x16x32_bf16(kf[n][0], qf0a, a, 0, 0, 0);
            a = __builtin_amdgcn_mfma_f32_16x16x32_bf16(kf[n][1], qf0b, a, 0, 0, 0);
            s0[n] = a;
        }
#pragma unroll
        for (int n = 0; n < 4; ++n) {
            f32x4 a = {0.f, 0.f, 0.f, 0.f};
            a = __builtin_amdgcn_mfma_f32_16x16x32_bf16(kf[n][0], qf1a, a, 0, 0, 0);
            a = __builtin_amdgcn_mfma_f32_16x16x32_bf16(kf[n][1], qf1b, a, 0, 0, 0);
            s1[n] = a;
        }
        softmax(s0, m0, oacc0, oaccS0);
        softmax(s1, m1, oacc1, oaccS1);
        // V fragments: read once, used by both q-halves
        bf16x8 vb[2][4];
#pragma unroll
        for (int kk = 0; kk < 2; ++kk)
#pragma unroll
            for (int n = 0; n < 4; ++n)
                vb[kk][n] = *(const bf16x8*)&Vl[cur][(n * 16 + l16) * 64 +
                                                     ((kk * 4 + lg) ^ sw) * 8];
        // half 0: P write, PV
        pwrite(s0);
#pragma unroll
        for (int kk = 0; kk < 2; ++kk) {
            int gp = (8 * kk + 2 * lg) ^ pmask;
            bf16x8 pa = *(const bf16x8*)((const char*)Pl[w] + l16 * 128 + gp * 8);
            oaccS0 = __builtin_amdgcn_mfma_f32_16x16x32_bf16(pa, ones, oaccS0, 0, 0, 0);
#pragma unroll
            for (int n = 0; n < 4; ++n)
                oacc0[n] = __builtin_amdgcn_mfma_f32_16x16x32_bf16(pa, vb[kk][n], oacc0[n], 0, 0, 0);
        }
        // half 1: overwrite P (per-wave DS ops in-order; h0 pa reads done)
        pwrite(s1);
#pragma unroll
        for (int kk = 0; kk < 2; ++kk) {
            int gp = (8 * kk + 2 * lg) ^ pmask;
            bf16x8 pa = *(const bf16x8*)((const char*)Pl[w] + l16 * 128 + gp * 8);
            oaccS1 = __builtin_amdgcn_mfma_f32_16x16x32_bf16(pa, ones, oaccS1, 0, 0, 0);
#pragma unroll
            for (int n = 0; n < 4; ++n)
                oacc1[n] = __builtin_amdgcn_mfma_f32_16x16x32_bf16(pa, vb[kk][n], oacc1[n], 0, 0, 0);
        }
    };

    stage(0, 0);
    for (int ti = 0; ti < 15; ++ti) {
        int cur = ti & 1;
        stage(cur ^ 1, (ti + 1) * 64);
        WAITV(2);   // my 2 loads for buf[cur] landed; next-tile 2 in flight
        SBAR();
        compute(cur);
        SBAR();
    }
    WAITV(0);
    SBAR();
    compute(1);

    const int b = bh >> 4, h = bh & 15;
#pragma unroll
    for (int r = 0; r < 4; ++r) {
        float inv = 1.f / oaccS0[r];
        size_t row = (size_t)(b * 1024 + qb * 256 + w * 32 + lg * 4 + r);
#pragma unroll
        for (int n = 0; n < 4; ++n)
            O[row * 1024 + h * 64 + n * 16 + l16] = f2bf(oacc0[n][r] * inv);
    }
#pragma unroll
    for (int r = 0; r < 4; ++r) {
        float inv = 1.f / oaccS1[r];
        size_t row = (size_t)(b * 1024 + qb * 256 + w * 32 + 16 + lg * 4 + r);
#pragma unroll
        for (int n = 0; n < 4; ++n)
            O[row * 1024 + h * 64 + n * 16 + l16] = f2bf(oacc1[n][r] * inv);
    }
}

// ---- Wo split-K reduce (3+1 bf16 partials) + bo + src resid -> LN1 --------
// emits xf (f32, final-residual) and xbf (bf16, FFN-up input)
__global__ __launch_bounds__(256) void k_lnwo(const short* __restrict__ p012,
                                              const short* __restrict__ p3,
                                              const float* __restrict__ bias,
                                              const float* __restrict__ resid,
                                              const float* __restrict__ g,
                                              const float* __restrict__ be,
                                              float* __restrict__ of,
                                              short* __restrict__ ob) {
    const int row = blockIdx.x, t = threadIdx.x;
    float4 x = ((const float4*)(resid + ((size_t)row << 10)))[t];
    float4 bv = ((const float4*)bias)[t];
    x.x += bv.x; x.y += bv.y; x.z += bv.z; x.w += bv.w;
#pragma unroll
    for (int kz = 0; kz < 3; ++kz) {
        short4v p = ((const short4v*)(p012 + (((size_t)kz * 4096 + row) << 10)))[t];
        x.x += bf2f(p[0]); x.y += bf2f(p[1]); x.z += bf2f(p[2]); x.w += bf2f(p[3]);
    }
    {
        short4v p = ((const short4v*)(p3 + ((size_t)row << 10)))[t];
        x.x += bf2f(p[0]); x.y += bf2f(p[1]); x.z += bf2f(p[2]); x.w += bf2f(p[3]);
    }
    float s = x.x + x.y + x.z + x.w;
    float s2 = x.x * x.x + x.y * x.y + x.z * x.z + x.w * x.w;
#pragma unroll
    for (int mm = 1; mm < 64; mm <<= 1) {
        s += __shfl_xor(s, mm);
        s2 += __shfl_xor(s2, mm);
    }
    __shared__ float red[8];
    if ((t & 63) == 0) { red[t >> 6] = s; red[4 + (t >> 6)] = s2; }
    __syncthreads();
    s = red[0] + red[1] + red[2] + red[3];
    s2 = red[4] + red[5] + red[6] + red[7];
    float mean = s * (1.f / 1024.f);
    float var = s2 * (1.f / 1024.f) - mean * mean;
    float rstd = rsqrtf(var + 1e-5f);
    int c = t * 4;
    float4 y;
    y.x = (x.x - mean) * rstd * g[c + 0] + be[c + 0];
    y.y = (x.y - mean) * rstd * g[c + 1] + be[c + 1];
    y.z = (x.z - mean) * rstd * g[c + 2] + be[c + 2];
    y.w = (x.w - mean) * rstd * g[c + 3] + be[c + 3];
    ((float4*)(of + ((size_t)row << 10)))[t] = y;
    short4v o;
    o[0] = f2bf(y.x); o[1] = f2bf(y.y); o[2] = f2bf(y.z); o[3] = f2bf(y.w);
    ((short4v*)(ob + ((size_t)row << 10)))[t] = o;
}

// ---- split-K reduce (4 contiguous bf16 partials) + bias + resid -> LN2 ----
__global__ __launch_bounds__(256) void k_lnred(const short* __restrict__ part,
                                               const float* __restrict__ bias,
                                               const float* __restrict__ resid,
                                               const float* __restrict__ g,
                                               const float* __restrict__ be,
                                               float* __restrict__ of) {
    const int row = blockIdx.x, t = threadIdx.x;
    float4 x = ((const float4*)(resid + ((size_t)row << 10)))[t];
    float4 bv = ((const float4*)bias)[t];
    x.x += bv.x; x.y += bv.y; x.z += bv.z; x.w += bv.w;
#pragma unroll
    for (int kz = 0; kz < 4; ++kz) {
        short4v p = ((const short4v*)(part + (((size_t)kz * 4096 + row) << 10)))[t];
        x.x += bf2f(p[0]); x.y += bf2f(p[1]); x.z += bf2f(p[2]); x.w += bf2f(p[3]);
    }
    float s = x.x + x.y + x.z + x.w;
    float s2 = x.x * x.x + x.y * x.y + x.z * x.z + x.w * x.w;
#pragma unroll
    for (int mm = 1; mm < 64; mm <<= 1) {
        s += __shfl_xor(s, mm);
        s2 += __shfl_xor(s2, mm);
    }
    __shared__ float red[8];
    if ((t & 63) == 0) { red[t >> 6] = s; red[4 + (t >> 6)] = s2; }
    __syncthreads();
    s = red[0] + red[1] + red[2] + red[3];
    s2 = red[4] + red[5] + red[6] + red[7];
    float mean = s * (1.f / 1024.f);
    float var = s2 * (1.f / 1024.f) - mean * mean;
    float rstd = rsqrtf(var + 1e-5f);
    int c = t * 4;
    float4 y;
    y.x = (x.x - mean) * rstd * g[c + 0] + be[c + 0];
    y.y = (x.y - mean) * rstd * g[c + 1] + be[c + 1];
    y.z = (x.z - mean) * rstd * g[c + 2] + be[c + 2];
    y.w = (x.w - mean) * rstd * g[c + 3] + be[c + 3];
    ((float4*)(of + ((size_t)row << 10)))[t] = y;
}

// ---------------- host ----------------
extern "C" void kernel_launch(void* const* d_in, const int* in_sizes, int n_in,
                              void* d_out, int out_size, void* d_ws, size_t ws_size,
                              hipStream_t stream) {
    (void)in_sizes; (void)n_in; (void)out_size; (void)ws_size;
    const float* src = (const float*)d_in[0];
    const float* Wq  = (const float*)d_in[1];
    const float* bq  = (const float*)d_in[2];
    const float* Wk  = (const float*)d_in[3];
    const float* bk  = (const float*)d_in[4];
    const float* Wv  = (const float*)d_in[5];
    const float* bv  = (const float*)d_in[6];
    const float* Wo  = (const float*)d_in[7];
    const float* bo  = (const float*)d_in[8];
    const float* g1  = (const float*)d_in[9];
    const float* be1 = (const float*)d_in[10];
    const float* W1  = (const float*)d_in[11];
    const float* b1  = (const float*)d_in[12];
    const float* W2  = (const float*)d_in[13];
    const float* b2  = (const float*)d_in[14];
    const float* g2  = (const float*)d_in[15];
    const float* be2 = (const float*)d_in[16];

    char* ws = (char*)d_ws;
    const size_t MB = 1048576;
    short* srcbf  = (short*)(ws + 0);
    short* Qb     = (short*)(ws + 8 * MB);
    short* Kb     = (short*)(ws + 16 * MB);
    short* VTb    = (short*)(ws + 24 * MB);
    short* h1     = (short*)(ws + 0);
    short* Obuf   = srcbf;
    short* W2T    = (short*)(ws + 32 * MB);
    float* xf     = (float*)(ws + 40 * MB);
    short* WqkvT  = (short*)(ws + 56 * MB);
    short* WoT    = (short*)(ws + 62 * MB);
    short* W1T    = (short*)(ws + 64 * MB);
    short* partWo0 = (short*)(ws + 8 * MB);   // Wo slices 0-2 (24MB)
    short* partWo3 = (short*)(ws + 72 * MB);  // Wo slice 3 (8MB)
    short* xbf    = (short*)(ws + 88 * MB);
    short* part   = (short*)(ws + 56 * MB);   // FFN-down [4][4096][1024] bf16

    // prep (all coalesced tiled transposes)
    k_cast<<<4096, 256, 0, stream>>>(src, srcbf, 1048576);
    k_tr3<<<dim3(1, 16, 48), 256, 0, stream>>>(Wq, Wk, Wv, WqkvT);
    k_tr<<<dim3(16, 16, 1), 256, 0, stream>>>(Wo, WoT, 1024, 1024, 0, 0);
    k_tr<<<dim3(64, 16, 1), 256, 0, stream>>>(W1, W1T, 1024, 4096, 0, 0);
    k_tr<<<dim3(16, 64, 1), 256, 0, stream>>>(W2, W2T, 4096, 1024, 0, 0);
    // QKV projection (M=4096, N=3072, K=1024)
    k_gemm8<0><<<dim3(12, 16, 1), 512, 0, stream>>>(srcbf, WqkvT, 1024, 16,
                                                    bq, bk, bv, Qb, Kb, VTb);
    // attention (8 waves, 256 q-rows per block)
    k_attn<<<dim3(64, 4), 512, 0, stream>>>(Qb, Kb, VTb, Obuf);
    // output projection (M=4096, N=1024, K=1024) -- split-K=4, NT=4
    k_gemm8<3><<<dim3(4, 16, 4), 512, 0, stream>>>(Obuf, WoT, 1024, 4,
                                                   nullptr, nullptr, nullptr,
                                                   partWo0, partWo3, nullptr);
    // reduce Wo partials + bo + src residual -> LN1 -> xf (f32) + xbf (bf16)
    k_lnwo<<<4096, 256, 0, stream>>>(partWo0, partWo3, bo, src, g1, be1, xf, xbf);
    // FFN up + relu (M=4096, N=4096, K=1024)
    k_gemm8<2><<<dim3(16, 16, 1), 512, 0, stream>>>(xbf, W1T, 1024, 16,
                                                    b1, nullptr, nullptr,
                                                    h1, nullptr, nullptr);
    // FFN down (M=4096, N=1024, K=4096) -- split-K=4, NT=16
    k_gemm8<3><<<dim3(4, 16, 4), 512, 0, stream>>>(h1, W2T, 4096, 16,
                                                   nullptr, nullptr, nullptr,
                                                   part, part + 3u * 4194304u,
                                                   nullptr);
    // reduce partials + b2 + xf residual -> LayerNorm2 -> d_out
    k_lnred<<<4096, 256, 0, stream>>>(part, b2, xf, g2, be2, (float*)d_out);
}

// Round 15
// 208.871 us; speedup vs baseline: 1.7360x; 1.5152x over previous
//
#include <hip/hip_runtime.h>
#include <hip/hip_bf16.h>

#define DEV __device__ __forceinline__

typedef __attribute__((ext_vector_type(8))) short bf16x8;
typedef __attribute__((ext_vector_type(4))) float f32x4;
typedef __attribute__((ext_vector_type(4))) short short4v;
typedef __attribute__((ext_vector_type(2))) unsigned uint2v;

DEV short f2bf(float f) {
    union { float f; unsigned u; } x; x.f = f;
    unsigned u = x.u;
    unsigned r = (u + 0x7fffu + ((u >> 16) & 1u)) >> 16;
    return (short)r;
}

DEV float bf2f(short s) {
    union { unsigned u; float f; } x;
    x.u = ((unsigned)(unsigned short)s) << 16;
    return x.f;
}

// pack 2 f32 -> 2 bf16 in one u32 (lo = a, hi = b)
DEV unsigned cvtpk(float a, float b) {
    unsigned r;
    asm("v_cvt_pk_bf16_f32 %0, %1, %2" : "=v"(r) : "v"(a), "v"(b));
    return r;
}

// async global->LDS, 16B per lane; LDS dest = wave-uniform base + lane*16
#define GLD16(g, l)                                                         \
    __builtin_amdgcn_global_load_lds(                                       \
        (const __attribute__((address_space(1))) void*)(g),                 \
        (__attribute__((address_space(3))) void*)(l), 16, 0, 0)

#define WAITV(n) asm volatile("s_waitcnt vmcnt(" #n ")" ::: "memory")
#define SBAR()   asm volatile("s_barrier" ::: "memory")
#define LGKMDRAIN() asm volatile("s_waitcnt lgkmcnt(0)" ::: "memory")

// ---------------- prep kernels ----------------

__global__ __launch_bounds__(256) void k_cast(const float* __restrict__ in,
                                              short* __restrict__ out, int n4) {
    int i = blockIdx.x * 256 + threadIdx.x;
    if (i >= n4) return;
    float4 v = ((const float4*)in)[i];
    short4v o;
    o[0] = f2bf(v.x); o[1] = f2bf(v.y); o[2] = f2bf(v.z); o[3] = f2bf(v.w);
    ((short4v*)out)[i] = o;
}

// tiled transpose+cast: out[(c)*R + r] = bf16(in[r*C + c]); R,C multiples of 64
__global__ __launch_bounds__(256) void k_tr(const float* __restrict__ in,
                                            short* __restrict__ out,
                                            int R, int C,
                                            long in_hs, long out_hs) {
    in  += (size_t)blockIdx.z * in_hs;
    out += (size_t)blockIdx.z * out_hs;
    __shared__ short tile[64][68];
    const int t = threadIdx.x;
    const int r0 = blockIdx.y * 64, c0 = blockIdx.x * 64;
    const int lr = t >> 4, lc4 = (t & 15) * 4;
#pragma unroll
    for (int it = 0; it < 4; ++it) {
        int r = lr + it * 16;
        float4 v = *(const float4*)(in + (size_t)(r0 + r) * C + c0 + lc4);
        tile[lc4 + 0][r] = f2bf(v.x);
        tile[lc4 + 1][r] = f2bf(v.y);
        tile[lc4 + 2][r] = f2bf(v.z);
        tile[lc4 + 3][r] = f2bf(v.w);
    }
    __syncthreads();
#pragma unroll
    for (int it = 0; it < 4; ++it) {
        int c = lr + it * 16;
        short4v o;
        o[0] = tile[c][lc4 + 0];
        o[1] = tile[c][lc4 + 1];
        o[2] = tile[c][lc4 + 2];
        o[3] = tile[c][lc4 + 3];
        *(short4v*)(out + (size_t)(c0 + c) * R + r0 + lc4) = o;
    }
}

// merged QKV per-head transpose: z in [0,48): p=z/16 selects Wq/Wk/Wv,
// h=z%16 the head. R=1024, C=64. out laid [p][h][64 k][1024 d].
__global__ __launch_bounds__(256) void k_tr3(const float* __restrict__ Wq,
                                             const float* __restrict__ Wk,
                                             const float* __restrict__ Wv,
                                             short* __restrict__ out) {
    const int z = blockIdx.z;
    const float* in = ((z < 16) ? Wq : (z < 32) ? Wk : Wv) +
                      (size_t)(z & 15) * 65536;
    short* o = out + (size_t)z * 65536;
    __shared__ short tile[64][68];
    const int t = threadIdx.x;
    const int r0 = blockIdx.y * 64;
    const int lr = t >> 4, lc4 = (t & 15) * 4;
#pragma unroll
    for (int it = 0; it < 4; ++it) {
        int r = lr + it * 16;
        float4 v = *(const float4*)(in + (size_t)(r0 + r) * 64 + lc4);
        tile[lc4 + 0][r] = f2bf(v.x);
        tile[lc4 + 1][r] = f2bf(v.y);
        tile[lc4 + 2][r] = f2bf(v.z);
        tile[lc4 + 3][r] = f2bf(v.w);
    }
    __syncthreads();
#pragma unroll
    for (int it = 0; it < 4; ++it) {
        int c = lr + it * 16;
        short4v ov;
        ov[0] = tile[c][lc4 + 0];
        ov[1] = tile[c][lc4 + 1];
        ov[2] = tile[c][lc4 + 2];
        ov[3] = tile[c][lc4 + 3];
        *(short4v*)(o + (size_t)c * 1024 + r0 + lc4) = ov;
    }
}

// ======== 256x256 GEMM, 2-barrier K-loop (R12, measured = R9) ===============
// C = A[M,K] * BT[N,K]^T. 512 thr = 8 waves (2M x 4N), wave tile 128x64, BK=64.
// blockIdx.z = split-K slice over K range [z*NT*64, (z+1)*NT*64).
// MODE 0: QKV scatter epilogue (Q pre-scaled by 1/8*log2e);
// MODE 2: bf16 relu(acc+bias);
// MODE 3: bf16 split-K partial -- slices 0..2 -> o0 + z*M*N, slice 3 -> o1
template <int MODE>
__global__ __launch_bounds__(512, 2) void k_gemm8(
    const short* __restrict__ A, const short* __restrict__ BT,
    int K, int NT,
    const float* __restrict__ f0, const float* __restrict__ f1,
    const float* __restrict__ f2,
    void* __restrict__ o0, void* __restrict__ o1, void* __restrict__ o2) {
    __shared__ short lds[2][2][2][128 * 64];   // [buf][op A=0,B=1][half][r*64+c]
    const int t = threadIdx.x;
    const int w = t >> 6, l = t & 63;
    const int l16 = l & 15, lg = l >> 4;
    const int wm = w >> 2, wn = w & 3;
    const int bn = blockIdx.x, bm = blockIdx.y;
    const int koff = blockIdx.z * NT * 64;
    const short* Ab = A + (size_t)bm * 256 * K + koff;
    const short* Bb = BT + (size_t)bn * 256 * K + koff;
    const int srow = l >> 3;                    // staging row within 8-row group
    const int scol = ((l & 7) ^ srow) * 8;      // pre-swizzled source col (shorts)
    const int offk0 = ((0 + lg) ^ (l16 & 7)) * 8;  // swizzled ds_read chunk, kk=0
    const int offk1 = ((4 + lg) ^ (l16 & 7)) * 8;  // kk=1

    f32x4 acc[8][4] = {};

    auto stg = [&](int buf, int op, int h, int kt) {
#pragma unroll
        for (int i = 0; i < 2; ++i) {
            int row = h * 128 + w * 16 + i * 8 + srow;
            GLD16((op ? Bb : Ab) + (size_t)row * K + (size_t)kt * 64 + scol,
                  &lds[buf][op][h][(w * 16 + i * 8) * 64]);
        }
    };

    // prologue: A(0),B(0)->buf0 (8 loads); B(t1)->buf1 (4 loads)
    stg(0, 0, 0, 0); stg(0, 0, 1, 0);
    stg(0, 1, 0, 0); stg(0, 1, 1, 0);
    const int t1p = (NT > 1) ? 1 : 0;
    stg(1, 1, 0, t1p); stg(1, 1, 1, t1p);
    WAITV(4);   // tile0 landed; B(t1) 4 loads in flight
    SBAR();

    for (int kt = 0; kt < NT; ++kt) {
        const int cur = kt & 1, nxt = cur ^ 1;
        const int t1 = (kt + 1 < NT) ? kt + 1 : NT - 1;
        const int t2 = (kt + 2 < NT) ? kt + 2 : NT - 1;

        // early stage: A(t1)->nxt (no reader conflict; hides under compute)
        stg(nxt, 0, 0, t1); stg(nxt, 0, 1, t1);

        bf16x8 a0[4][2], a1[4][2], b0[2][2], b1[2][2];
#pragma unroll
        for (int m = 0; m < 4; ++m) {
            a0[m][0] = *(const bf16x8*)&lds[cur][0][wm][(m * 16 + l16) * 64 + offk0];
            a0[m][1] = *(const bf16x8*)&lds[cur][0][wm][(m * 16 + l16) * 64 + offk1];
        }
#pragma unroll
        for (int n = 0; n < 2; ++n) {
            int r = (wn & 1) * 64 + n * 16 + l16;
            b0[n][0] = *(const bf16x8*)&lds[cur][1][wn >> 1][r * 64 + offk0];
            b0[n][1] = *(const bf16x8*)&lds[cur][1][wn >> 1][r * 64 + offk1];
            int r2 = (wn & 1) * 64 + (n + 2) * 16 + l16;
            b1[n][0] = *(const bf16x8*)&lds[cur][1][wn >> 1][r2 * 64 + offk0];
            b1[n][1] = *(const bf16x8*)&lds[cur][1][wn >> 1][r2 * 64 + offk1];
        }
        __builtin_amdgcn_s_setprio(1);
#pragma unroll
        for (int m = 0; m < 4; ++m)
#pragma unroll
            for (int n = 0; n < 2; ++n) {
                acc[m][n] = __builtin_amdgcn_mfma_f32_16x16x32_bf16(a0[m][0], b0[n][0], acc[m][n], 0, 0, 0);
                acc[m][n] = __builtin_amdgcn_mfma_f32_16x16x32_bf16(a0[m][1], b0[n][1], acc[m][n], 0, 0, 0);
                acc[m][n + 2] = __builtin_amdgcn_mfma_f32_16x16x32_bf16(a0[m][0], b1[n][0], acc[m][n + 2], 0, 0, 0);
                acc[m][n + 2] = __builtin_amdgcn_mfma_f32_16x16x32_bf16(a0[m][1], b1[n][1], acc[m][n + 2], 0, 0, 0);
            }
        __builtin_amdgcn_s_setprio(0);
#pragma unroll
        for (int m = 0; m < 4; ++m) {
            a1[m][0] = *(const bf16x8*)&lds[cur][0][wm][((m + 4) * 16 + l16) * 64 + offk0];
            a1[m][1] = *(const bf16x8*)&lds[cur][0][wm][((m + 4) * 16 + l16) * 64 + offk1];
        }
        __builtin_amdgcn_s_setprio(1);
#pragma unroll
        for (int m = 0; m < 4; ++m)
#pragma unroll
            for (int n = 0; n < 2; ++n) {
                acc[m + 4][n + 2] = __builtin_amdgcn_mfma_f32_16x16x32_bf16(a1[m][0], b1[n][0], acc[m + 4][n + 2], 0, 0, 0);
                acc[m + 4][n + 2] = __builtin_amdgcn_mfma_f32_16x16x32_bf16(a1[m][1], b1[n][1], acc[m + 4][n + 2], 0, 0, 0);
                acc[m + 4][n] = __builtin_amdgcn_mfma_f32_16x16x32_bf16(a1[m][0], b0[n][0], acc[m + 4][n], 0, 0, 0);
                acc[m + 4][n] = __builtin_amdgcn_mfma_f32_16x16x32_bf16(a1[m][1], b0[n][1], acc[m + 4][n], 0, 0, 0);
            }
        __builtin_amdgcn_s_setprio(0);

        LGKMDRAIN();   // all cur reads retired in this wave
        SBAR();        // ... in every wave -> safe to overwrite cur-B
        stg(cur, 1, 0, t2); stg(cur, 1, 1, t2);   // B(t2)->cur (4 loads)
        WAITV(4);      // A(t1),B(t1) retired; only B(t2)'s 4 in flight
        SBAR();        // all waves -> t1 fully in LDS
    }
    WAITV(0);          // retire clamped trailing stages before exit

    const int N = gridDim.x * 256;
#pragma unroll
    for (int m = 0; m < 8; ++m) {
        int rowbase = bm * 256 + wm * 128 + m * 16 + lg * 4;
#pragma unroll
        for (int n = 0; n < 4; ++n) {
            int col = bn * 256 + wn * 64 + n * 16 + l16;
            if constexpr (MODE == 0) {
                int p = col >> 10, c1 = col & 1023;
                int hh = c1 >> 6, dk = c1 & 63;
                const float* bias = (p == 0) ? f0 : (p == 1) ? f1 : f2;
                float bvl = bias[c1];
                // fold softmax scale*log2e into Q
                float qs = (p == 0) ? 0.18033688011112042f : 1.0f;
                int b = rowbase >> 10, s = rowbase & 1023;
                if (p == 2) {
                    short4v vv;
#pragma unroll
                    for (int rr = 0; rr < 4; ++rr) vv[rr] = f2bf(acc[m][n][rr] + bvl);
                    *(short4v*)((short*)o2 + (((size_t)(b * 16 + hh) * 64 + dk) << 10) + s) = vv;
                } else {
                    short* dst = (p == 0) ? (short*)o0 : (short*)o1;
#pragma unroll
                    for (int rr = 0; rr < 4; ++rr)
                        dst[(((size_t)(b * 16 + hh) << 10) + s + rr) * 64 + dk] =
                            f2bf((acc[m][n][rr] + bvl) * qs);
                }
            } else if constexpr (MODE == 2) {
                float bvl = f0[col];
#pragma unroll
                for (int rr = 0; rr < 4; ++rr) {
                    size_t idx = (size_t)(rowbase + rr) * N + col;
                    float y = acc[m][n][rr] + bvl;
                    ((short*)o0)[idx] = f2bf(y > 0.f ? y : 0.f);
                }
            } else {  // MODE 3: bf16 split-K partial; z<3 -> o0+z*M*N, z=3 -> o1
                const int Mtot = gridDim.y * 256;
                short* dst = (blockIdx.z < 3)
                    ? (short*)o0 + (size_t)blockIdx.z * Mtot * N
                    : (short*)o1;
                size_t base = (size_t)rowbase * N + col;
#pragma unroll
                for (int rr = 0; rr < 4; ++rr)
                    dst[base + (size_t)rr * N] = f2bf(acc[m][n][rr]);
            }
        }
    }
}

// ------- flash attention (R12-exact revert): 8 waves, QBLK=128 --------------
// grid (64, 8): blockIdx.x = b*16+h, blockIdx.y = q-block of 128 rows.
// 8 waves, each owns 16 q rows; one 64-kv K/V tile feeds all 8 waves.
// Q pre-scaled by 1/8*log2e. Row-sum ls accumulated by mfma(P, ones).
// Softmax INLINE in compute (nested lambdas with array-ref params caused
// scratch spills in R13/R14 -- rule #20 via addressability).
__global__ __launch_bounds__(512, 4) void k_attn(const short* __restrict__ Q,
                                                 const short* __restrict__ Kt,
                                                 const short* __restrict__ VT,
                                                 short* __restrict__ O) {
    __shared__ short Kl[2][64 * 64];   // [buf][kv_local][dk-chunk swz]
    __shared__ short Vl[2][64 * 64];   // [buf][dk][t-chunk swz]
    __shared__ short Pl[8][16 * 64];   // per-wave [q=l16][kv granule-swz]
    const int bh = blockIdx.x;
    const int qb = blockIdx.y;
    const int t = threadIdx.x;
    const int w = t >> 6, l = t & 63;
    const int l16 = l & 15, lg = l >> 4;
    const int sw = l16 & 7;                       // K/V chunk XOR
    const int pmask = (l16 & 7) << 1;             // P 8B-granule XOR (even)
    const int srow = l >> 3;
    const int scol = ((l & 7) ^ srow) * 8;        // pre-swizzled global col

    const short* Qb = Q + ((size_t)bh * 1024 + qb * 128 + w * 16 + l16) * 64 + lg * 8;
    bf16x8 qf0 = *(const bf16x8*)Qb;
    bf16x8 qf1 = *(const bf16x8*)(Qb + 32);

    const short* Kbase = Kt + (size_t)bh * (1024 * 64);
    const short* Vbase = VT + (size_t)bh * (64 * 1024);

    const float THR = 11.5415603f;    // 8 nats in log2

    bf16x8 ones;
#pragma unroll
    for (int i = 0; i < 8; ++i) ones[i] = (short)0x3F80;  // bf16 1.0

    float m = -1e30f;                 // per-lane running max for q-row l16
    f32x4 oacc[4] = {};
    f32x4 oaccS = {};                 // row-sum accumulator (P x ones)

    // wave w stages K rows [w*8,+8) and V rows [w*8,+8): 2 GLD16 per tile
    auto stage = [&](int buf, int t0) {
        int roww = w * 8;
        GLD16(Kbase + (size_t)(t0 + roww + srow) * 64 + scol,
              &Kl[buf][roww * 64]);
        GLD16(Vbase + (size_t)(roww + srow) * 1024 + t0 + scol,
              &Vl[buf][roww * 64]);
    };

    auto compute = [&](int cur) {
        f32x4 s[4];
#pragma unroll
        for (int n = 0; n < 4; ++n) {
            bf16x8 kf0 = *(const bf16x8*)&Kl[cur][(n * 16 + l16) * 64 + (lg ^ sw) * 8];
            bf16x8 kf1 = *(const bf16x8*)&Kl[cur][(n * 16 + l16) * 64 + ((4 + lg) ^ sw) * 8];
            f32x4 a = {0.f, 0.f, 0.f, 0.f};
            // SWAPPED operands: D[i=kv][j=q] -> col l16 = q-row, row = kv
            a = __builtin_amdgcn_mfma_f32_16x16x32_bf16(kf0, qf0, a, 0, 0, 0);
            a = __builtin_amdgcn_mfma_f32_16x16x32_bf16(kf1, qf1, a, 0, 0, 0);
            s[n] = a;   // Q pre-scaled; s[n][r]: q=l16, kv=n*16+lg*4+r
        }
        // in-lane max over 16 values (max3-friendly triples) + 2 shfl
        float m1 = fmaxf(fmaxf(s[0][0], s[0][1]), s[0][2]);
        float m2 = fmaxf(fmaxf(s[0][3], s[1][0]), s[1][1]);
        float m3 = fmaxf(fmaxf(s[1][2], s[1][3]), s[2][0]);
        float m4 = fmaxf(fmaxf(s[2][1], s[2][2]), s[2][3]);
        float m5 = fmaxf(fmaxf(s[3][0], s[3][1]), s[3][2]);
        float mx = fmaxf(fmaxf(m1, m2), m3);
        mx = fmaxf(fmaxf(m4, m5), fmaxf(mx, s[3][3]));
        mx = fmaxf(mx, __shfl_xor(mx, 16));
        mx = fmaxf(mx, __shfl_xor(mx, 32));

        if (__any(mx > m + THR)) {
            float mn = fmaxf(m, mx);
            float al = exp2f(m - mn);
            m = mn;
#pragma unroll
            for (int n = 0; n < 4; ++n)
#pragma unroll
                for (int r = 0; r < 4; ++r) s[n][r] = exp2f(s[n][r] - m);
#pragma unroll
            for (int r = 0; r < 4; ++r) {
                float alr = __shfl(al, lg * 4 + r);   // al for q-row lg*4+r
                oaccS[r] *= alr;
#pragma unroll
                for (int n = 0; n < 4; ++n) oacc[n][r] *= alr;
            }
        } else {   // T13 defer: keep m, skip rescale (P bounded by 2^THR)
#pragma unroll
            for (int n = 0; n < 4; ++n)
#pragma unroll
                for (int r = 0; r < 4; ++r) s[n][r] = exp2f(s[n][r] - m);
        }
        // P write: row q=l16 (stride 128B), kv shorts n*16+lg*4.. as b64,
        // 8B-granule g = n*4+lg XOR pmask (even mask keeps pair adjacency)
#pragma unroll
        for (int n = 0; n < 4; ++n) {
            uint2v pv;
            pv[0] = cvtpk(s[n][0], s[n][1]);
            pv[1] = cvtpk(s[n][2], s[n][3]);
            int g = (n * 4 + lg) ^ pmask;
            *(uint2v*)((char*)Pl[w] + l16 * 128 + g * 8) = pv;
        }
        // PV + row-sum: pa = P[q=l16][kv 32kk+8lg..+8] (granule pair, swz)
#pragma unroll
        for (int kk = 0; kk < 2; ++kk) {
            int gp = (8 * kk + 2 * lg) ^ pmask;
            bf16x8 pa = *(const bf16x8*)((const char*)Pl[w] + l16 * 128 + gp * 8);
            oaccS = __builtin_amdgcn_mfma_f32_16x16x32_bf16(pa, ones, oaccS, 0, 0, 0);
#pragma unroll
            for (int n = 0; n < 4; ++n) {
                bf16x8 vb = *(const bf16x8*)&Vl[cur][(n * 16 + l16) * 64 +
                                                     ((kk * 4 + lg) ^ sw) * 8];
                oacc[n] = __builtin_amdgcn_mfma_f32_16x16x32_bf16(pa, vb, oacc[n],
                                                                  0, 0, 0);
            }
        }
    };

    stage(0, 0);
    for (int ti = 0; ti < 15; ++ti) {
        int cur = ti & 1;
        stage(cur ^ 1, (ti + 1) * 64);
        WAITV(2);   // my 2 loads for buf[cur] landed; next-tile 2 in flight
        SBAR();
        compute(cur);
        SBAR();
    }
    WAITV(0);
    SBAR();
    compute(1);

    const int b = bh >> 4, h = bh & 15;
#pragma unroll
    for (int r = 0; r < 4; ++r) {
        float inv = 1.f / oaccS[r];   // denom for q-row lg*4+r (all l16 equal)
        size_t row = (size_t)(b * 1024 + qb * 128 + w * 16 + lg * 4 + r);
#pragma unroll
        for (int n = 0; n < 4; ++n)
            O[row * 1024 + h * 64 + n * 16 + l16] = f2bf(oacc[n][r] * inv);
    }
}

// ---- Wo split-K reduce (3+1 bf16 partials) + bo + src resid -> LN1 --------
// emits xf (f32, final-residual) and xbf (bf16, FFN-up input)
__global__ __launch_bounds__(256) void k_lnwo(const short* __restrict__ p012,
                                              const short* __restrict__ p3,
                                              const float* __restrict__ bias,
                                              const float* __restrict__ resid,
                                              const float* __restrict__ g,
                                              const float* __restrict__ be,
                                              float* __restrict__ of,
                                              short* __restrict__ ob) {
    const int row = blockIdx.x, t = threadIdx.x;
    float4 x = ((const float4*)(resid + ((size_t)row << 10)))[t];
    float4 bv = ((const float4*)bias)[t];
    x.x += bv.x; x.y += bv.y; x.z += bv.z; x.w += bv.w;
#pragma unroll
    for (int kz = 0; kz < 3; ++kz) {
        short4v p = ((const short4v*)(p012 + (((size_t)kz * 4096 + row) << 10)))[t];
        x.x += bf2f(p[0]); x.y += bf2f(p[1]); x.z += bf2f(p[2]); x.w += bf2f(p[3]);
    }
    {
        short4v p = ((const short4v*)(p3 + ((size_t)row << 10)))[t];
        x.x += bf2f(p[0]); x.y += bf2f(p[1]); x.z += bf2f(p[2]); x.w += bf2f(p[3]);
    }
    float s = x.x + x.y + x.z + x.w;
    float s2 = x.x * x.x + x.y * x.y + x.z * x.z + x.w * x.w;
#pragma unroll
    for (int mm = 1; mm < 64; mm <<= 1) {
        s += __shfl_xor(s, mm);
        s2 += __shfl_xor(s2, mm);
    }
    __shared__ float red[8];
    if ((t & 63) == 0) { red[t >> 6] = s; red[4 + (t >> 6)] = s2; }
    __syncthreads();
    s = red[0] + red[1] + red[2] + red[3];
    s2 = red[4] + red[5] + red[6] + red[7];
    float mean = s * (1.f / 1024.f);
    float var = s2 * (1.f / 1024.f) - mean * mean;
    float rstd = rsqrtf(var + 1e-5f);
    int c = t * 4;
    float4 y;
    y.x = (x.x - mean) * rstd * g[c + 0] + be[c + 0];
    y.y = (x.y - mean) * rstd * g[c + 1] + be[c + 1];
    y.z = (x.z - mean) * rstd * g[c + 2] + be[c + 2];
    y.w = (x.w - mean) * rstd * g[c + 3] + be[c + 3];
    ((float4*)(of + ((size_t)row << 10)))[t] = y;
    short4v o;
    o[0] = f2bf(y.x); o[1] = f2bf(y.y); o[2] = f2bf(y.z); o[3] = f2bf(y.w);
    ((short4v*)(ob + ((size_t)row << 10)))[t] = o;
}

// ---- split-K reduce (4 contiguous bf16 partials) + bias + resid -> LN2 ----
__global__ __launch_bounds__(256) void k_lnred(const short* __restrict__ part,
                                               const float* __restrict__ bias,
                                               const float* __restrict__ resid,
                                               const float* __restrict__ g,
                                               const float* __restrict__ be,
                                               float* __restrict__ of) {
    const int row = blockIdx.x, t = threadIdx.x;
    float4 x = ((const float4*)(resid + ((size_t)row << 10)))[t];
    float4 bv = ((const float4*)bias)[t];
    x.x += bv.x; x.y += bv.y; x.z += bv.z; x.w += bv.w;
#pragma unroll
    for (int kz = 0; kz < 4; ++kz) {
        short4v p = ((const short4v*)(part + (((size_t)kz * 4096 + row) << 10)))[t];
        x.x += bf2f(p[0]); x.y += bf2f(p[1]); x.z += bf2f(p[2]); x.w += bf2f(p[3]);
    }
    float s = x.x + x.y + x.z + x.w;
    float s2 = x.x * x.x + x.y * x.y + x.z * x.z + x.w * x.w;
#pragma unroll
    for (int mm = 1; mm < 64; mm <<= 1) {
        s += __shfl_xor(s, mm);
        s2 += __shfl_xor(s2, mm);
    }
    __shared__ float red[8];
    if ((t & 63) == 0) { red[t >> 6] = s; red[4 + (t >> 6)] = s2; }
    __syncthreads();
    s = red[0] + red[1] + red[2] + red[3];
    s2 = red[4] + red[5] + red[6] + red[7];
    float mean = s * (1.f / 1024.f);
    float var = s2 * (1.f / 1024.f) - mean * mean;
    float rstd = rsqrtf(var + 1e-5f);
    int c = t * 4;
    float4 y;
    y.x = (x.x - mean) * rstd * g[c + 0] + be[c + 0];
    y.y = (x.y - mean) * rstd * g[c + 1] + be[c + 1];
    y.z = (x.z - mean) * rstd * g[c + 2] + be[c + 2];
    y.w = (x.w - mean) * rstd * g[c + 3] + be[c + 3];
    ((float4*)(of + ((size_t)row << 10)))[t] = y;
}

// ---------------- host ----------------
extern "C" void kernel_launch(void* const* d_in, const int* in_sizes, int n_in,
                              void* d_out, int out_size, void* d_ws, size_t ws_size,
                              hipStream_t stream) {
    (void)in_sizes; (void)n_in; (void)out_size; (void)ws_size;
    const float* src = (const float*)d_in[0];
    const float* Wq  = (const float*)d_in[1];
    const float* bq  = (const float*)d_in[2];
    const float* Wk  = (const float*)d_in[3];
    const float* bk  = (const float*)d_in[4];
    const float* Wv  = (const float*)d_in[5];
    const float* bv  = (const float*)d_in[6];
    const float* Wo  = (const float*)d_in[7];
    const float* bo  = (const float*)d_in[8];
    const float* g1  = (const float*)d_in[9];
    const float* be1 = (const float*)d_in[10];
    const float* W1  = (const float*)d_in[11];
    const float* b1  = (const float*)d_in[12];
    const float* W2  = (const float*)d_in[13];
    const float* b2  = (const float*)d_in[14];
    const float* g2  = (const float*)d_in[15];
    const float* be2 = (const float*)d_in[16];

    char* ws = (char*)d_ws;
    const size_t MB = 1048576;
    short* srcbf  = (short*)(ws + 0);
    short* Qb     = (short*)(ws + 8 * MB);
    short* Kb     = (short*)(ws + 16 * MB);
    short* VTb    = (short*)(ws + 24 * MB);
    short* h1     = (short*)(ws + 0);
    short* Obuf   = srcbf;
    short* W2T    = (short*)(ws + 32 * MB);
    float* xf     = (float*)(ws + 40 * MB);
    short* WqkvT  = (short*)(ws + 56 * MB);
    short* WoT    = (short*)(ws + 62 * MB);
    short* W1T    = (short*)(ws + 64 * MB);
    short* partWo0 = (short*)(ws + 8 * MB);   // Wo slices 0-2 (24MB)
    short* partWo3 = (short*)(ws + 72 * MB);  // Wo slice 3 (8MB)
    short* xbf    = (short*)(ws + 88 * MB);
    short* part   = (short*)(ws + 56 * MB);   // FFN-down [4][4096][1024] bf16

    // prep (all coalesced tiled transposes)
    k_cast<<<4096, 256, 0, stream>>>(src, srcbf, 1048576);
    k_tr3<<<dim3(1, 16, 48), 256, 0, stream>>>(Wq, Wk, Wv, WqkvT);
    k_tr<<<dim3(16, 16, 1), 256, 0, stream>>>(Wo, WoT, 1024, 1024, 0, 0);
    k_tr<<<dim3(64, 16, 1), 256, 0, stream>>>(W1, W1T, 1024, 4096, 0, 0);
    k_tr<<<dim3(16, 64, 1), 256, 0, stream>>>(W2, W2T, 4096, 1024, 0, 0);
    // QKV projection (M=4096, N=3072, K=1024)
    k_gemm8<0><<<dim3(12, 16, 1), 512, 0, stream>>>(srcbf, WqkvT, 1024, 16,
                                                    bq, bk, bv, Qb, Kb, VTb);
    // attention (8 waves, 128 q-rows per block)
    k_attn<<<dim3(64, 8), 512, 0, stream>>>(Qb, Kb, VTb, Obuf);
    // output projection (M=4096, N=1024, K=1024) -- split-K=4, NT=4
    k_gemm8<3><<<dim3(4, 16, 4), 512, 0, stream>>>(Obuf, WoT, 1024, 4,
                                                   nullptr, nullptr, nullptr,
                                                   partWo0, partWo3, nullptr);
    // reduce Wo partials + bo + src residual -> LN1 -> xf (f32) + xbf (bf16)
    k_lnwo<<<4096, 256, 0, stream>>>(partWo0, partWo3, bo, src, g1, be1, xf, xbf);
    // FFN up + relu (M=4096, N=4096, K=1024)
    k_gemm8<2><<<dim3(16, 16, 1), 512, 0, stream>>>(xbf, W1T, 1024, 16,
                                                    b1, nullptr, nullptr,
                                                    h1, nullptr, nullptr);
    // FFN down (M=4096, N=1024, K=4096) -- split-K=4, NT=16
    k_gemm8<3><<<dim3(4, 16, 4), 512, 0, stream>>>(h1, W2T, 4096, 16,
                                                   nullptr, nullptr, nullptr,
                                                   part, part + 3u * 4194304u,
                                                   nullptr);
    // reduce partials + b2 + xf residual -> LayerNorm2 -> d_out
    k_lnred<<<4096, 256, 0, stream>>>(part, b2, xf, g2, be2, (float*)d_out);
}